// Round 1
// baseline (303.324 us; speedup 1.0000x reference)
//
#include <hip/hip_runtime.h>

#define TOKENS 16384
#define HID 2048
#define NE 64

// ws layout (floats):
//   wt   [0, 131072)                    : gate_w transposed -> [2048][64]
//   part [131072, 131072+2*1048576)     : partial logits [2 k-halves][16384][64]
//   bp   [2228224, 2228224+32768)       : per-block epilogue partials [256][128]
#define WS_WT   0
#define WS_PART 131072
#define WS_BP   (131072 + 2097152)

__global__ __launch_bounds__(256) void k_transpose(const float* __restrict__ gw,
                                                   float* __restrict__ wt) {
  int idx = blockIdx.x * 256 + threadIdx.x;      // 131072 total
  int e = idx & 63, k = idx >> 6;
  wt[idx] = gw[e * HID + k];
}

__global__ __launch_bounds__(256) void k_logits(const float* __restrict__ hid,
                                                const float* __restrict__ wt,
                                                float* __restrict__ part) {
  const int tg   = blockIdx.x & 255;   // token group (64 tokens)
  const int half = blockIdx.x >> 8;    // K half
  const int wave = threadIdx.x >> 6;
  const int lane = threadIdx.x & 63;
  const int t    = tg * 64 + lane;     // lane = token
  const int kbase = half * 1024 + wave * 256;

  const float* hp = hid + (size_t)t * HID + kbase;
  const float* wp = wt + (size_t)kbase * 64;

  float acc[64];
  #pragma unroll
  for (int e = 0; e < 64; ++e) acc[e] = 0.f;

  #pragma unroll 2
  for (int kb = 0; kb < 256; kb += 4) {
    const float4 h4 = *reinterpret_cast<const float4*>(hp + kb);
    const float hv[4] = {h4.x, h4.y, h4.z, h4.w};
    #pragma unroll
    for (int j = 0; j < 4; ++j) {
      const float* wr = wp + (size_t)(kb + j) * 64;  // wave-uniform -> s_load
      #pragma unroll
      for (int e = 0; e < 64; ++e) acc[e] = fmaf(wr[e], hv[j], acc[e]);
    }
  }

  // reduce the 4 waves' K-quarters into one per-token row
  __shared__ float buf[64][65];
  for (int i = threadIdx.x; i < 64 * 65; i += 256) (&buf[0][0])[i] = 0.f;
  __syncthreads();
  for (int w = 0; w < 4; ++w) {
    if (wave == w) {
      #pragma unroll
      for (int e = 0; e < 64; ++e) buf[lane][e] += acc[e];
    }
    __syncthreads();
  }
  for (int i = threadIdx.x; i < 4096; i += 256) {
    int r = i >> 6, c = i & 63;
    part[((size_t)half * TOKENS + (size_t)tg * 64 + r) * 64 + c] = buf[r][c];
  }
}

__global__ __launch_bounds__(64) void k_finish(const float* __restrict__ part,
                                               float* __restrict__ out,
                                               float* __restrict__ bp) {
  const int lane = threadIdx.x;
  const int t = blockIdx.x * 64 + lane;

  float lg[64];
  const float* p0 = part + (size_t)t * 64;
  const float* p1 = part + (size_t)TOKENS * 64 + (size_t)t * 64;
  #pragma unroll
  for (int e = 0; e < 64; e += 4) {
    float4 a = *reinterpret_cast<const float4*>(p0 + e);
    float4 b = *reinterpret_cast<const float4*>(p1 + e);
    lg[e]     = a.x + b.x;
    lg[e + 1] = a.y + b.y;
    lg[e + 2] = a.z + b.z;
    lg[e + 3] = a.w + b.w;
  }

  float m = lg[0];
  #pragma unroll
  for (int e = 1; e < 64; ++e) m = fmaxf(m, lg[e]);
  float s = 0.f;
  #pragma unroll
  for (int e = 0; e < 64; ++e) { lg[e] = __expf(lg[e] - m); s += lg[e]; }
  const float inv = 1.f / s;

  // top-2 on exp values (monotone in logits); strict '>' == lax.top_k tie-break
  float b0 = -1.f, b1 = -1.f;
  int i0 = 0, i1 = 0;
  #pragma unroll
  for (int e = 0; e < 64; ++e) {
    float p = lg[e];
    if (p > b0)      { b1 = b0; i1 = i0; b0 = p; i0 = e; }
    else if (p > b1) { b1 = p; i1 = e; }
  }
  const float rs = 1.f / (b0 + b1);
  out[(size_t)t * 2]                  = b0 * rs;
  out[(size_t)t * 2 + 1]              = b1 * rs;
  out[(size_t)TOKENS * 2 + t * 2]     = (float)i0;  // indices as float32
  out[(size_t)TOKENS * 2 + t * 2 + 1] = (float)i1;

  // per-expert partials: sum of softmax probs (butterfly) + top-2 counts (ballot)
  float my_sp = 0.f, my_cnt = 0.f;
  #pragma unroll
  for (int e = 0; e < 64; ++e) {
    float x = lg[e] * inv;
    #pragma unroll
    for (int d = 1; d < 64; d <<= 1) x += __shfl_xor(x, d);
    float c = (float)(__popcll(__ballot(i0 == e)) + __popcll(__ballot(i1 == e)));
    if (lane == e) { my_sp = x; my_cnt = c; }
  }
  bp[(size_t)blockIdx.x * 128 + lane]      = my_sp;
  bp[(size_t)blockIdx.x * 128 + 64 + lane] = my_cnt;
}

__global__ __launch_bounds__(128) void k_loss(const float* __restrict__ bp,
                                              float* __restrict__ out) {
  const int tid = threadIdx.x;
  float s = 0.f;
  for (int b = 0; b < 256; ++b) s += bp[b * 128 + tid];
  __shared__ float red[128];
  red[tid] = s;
  __syncthreads();
  if (tid < 64) {
    float v = red[tid] * red[64 + tid];  // sumprob_e * count_e
    #pragma unroll
    for (int d = 1; d < 64; d <<= 1) v += __shfl_xor(v, d);
    if (tid == 0)
      out[(size_t)TOKENS * 4] = 0.01f * 64.f * v / ((float)TOKENS * (float)TOKENS);
  }
}

extern "C" void kernel_launch(void* const* d_in, const int* in_sizes, int n_in,
                              void* d_out, int out_size, void* d_ws, size_t ws_size,
                              hipStream_t stream) {
  (void)in_sizes; (void)n_in; (void)out_size; (void)ws_size;
  const float* hid = (const float*)d_in[0];
  const float* gw  = (const float*)d_in[1];
  float* out  = (float*)d_out;
  float* ws   = (float*)d_ws;
  float* wt   = ws + WS_WT;
  float* part = ws + WS_PART;
  float* bp   = ws + WS_BP;

  k_transpose<<<512, 256, 0, stream>>>(gw, wt);
  k_logits<<<512, 256, 0, stream>>>(hid, wt, part);
  k_finish<<<256, 64, 0, stream>>>(part, out, bp);
  k_loss<<<1, 128, 0, stream>>>(bp, out);
}

// Round 2
// 172.977 us; speedup vs baseline: 1.7536x; 1.7536x over previous
//
#include <hip/hip_runtime.h>
#include <math.h>

#define TOKENS 16384
#define HID    2048
#define NE     64
#define KC     128              // K per LDS chunk
#define NCHUNK (HID / KC)       // 16
#define TB     32               // tokens per block
#define TW     8                // tokens per wave

typedef float v2f __attribute__((ext_vector_type(2)));
typedef float v4f __attribute__((ext_vector_type(4)));

// ws layout (floats):
//   wt4 [0, 131072)          : weights k-quad-interleaved: float4[kq=512][e=64]
//   bp  [131072, +65536)     : per-block aux partials [512][128] (sp | cnt)
//   g2  [196608, +8192)      : stage-1 loss partials [64][128]
#define WS_WT4 0
#define WS_BP  131072
#define WS_G2  (131072 + 65536)

__global__ __launch_bounds__(256) void k_pack(const float* __restrict__ gw,
                                              float* __restrict__ wt4) {
  int tid = blockIdx.x * 256 + threadIdx.x;   // 32768 = 512 kq * 64 e
  int e = tid & 63, kq = tid >> 6;
  v4f v = *reinterpret_cast<const v4f*>(gw + (size_t)e * HID + kq * 4);
  *reinterpret_cast<v4f*>(wt4 + (size_t)tid * 4) = v;
}

__device__ __forceinline__ void gl16(const float* g, const float* l) {
  __builtin_amdgcn_global_load_lds(
      (const __attribute__((address_space(1))) void*)g,
      (__attribute__((address_space(3))) void*)l, 16, 0, 0);
}

__global__ __launch_bounds__(256, 2) void k_main(const float* __restrict__ hid,
                                                 const float* __restrict__ wt4,
                                                 float* __restrict__ out,
                                                 float* __restrict__ bp) {
  // LDS: [0,8192) floats = weight chunk as float4[32 kq][64 e] (32KB)
  //      [8192,12288) floats = hidden tile [32 tok][128 k]     (16KB)
  __shared__ float lds[12288];
  const int tid  = threadIdx.x;
  const int wave = tid >> 6, lane = tid & 63;
  const int tok0 = blockIdx.x * TB;

  // staging source pointers (per-thread); LDS dests are wave-uniform bases
  const float* pw = wt4 + (size_t)tid * 4;     // w: unit = j*256+tid, j=0..7
  const float* gh[4];                          // h: i = j*256+tid; row=i>>5; c16=i&31
  #pragma unroll
  for (int j = 0; j < 4; ++j) {
    int i = j * 256 + tid;
    gh[j] = hid + (size_t)(tok0 + (i >> 5)) * HID + (i & 31) * 4;
  }
  int hoff = 0;

  v2f acc[TW];
  #pragma unroll
  for (int t = 0; t < TW; ++t) acc[t] = (v2f){0.f, 0.f};

  for (int c = 0; c < NCHUNK; ++c) {
    // ---- stage: 8 weight units + 4 hidden units per thread ----
    #pragma unroll
    for (int j = 0; j < 8; ++j)
      gl16(pw + j * 1024, lds + j * 1024 + wave * 256);
    #pragma unroll
    for (int j = 0; j < 4; ++j)
      gl16(gh[j] + hoff, lds + 8192 + j * 1024 + wave * 256);
    __syncthreads();

    // ---- compute ----
    const v4f* wq = reinterpret_cast<const v4f*>(lds);          // [kq*64 + lane]
    const float* hb = lds + 8192 + wave * TW * KC;              // wave's 8 rows
    #pragma unroll 8
    for (int kq = 0; kq < 32; ++kq) {
      v4f w4 = wq[kq * 64 + lane];
      v2f w01 = {w4.x, w4.y}, w23 = {w4.z, w4.w};
      #pragma unroll
      for (int t = 0; t < TW; ++t) {
        v4f h4 = *reinterpret_cast<const v4f*>(hb + t * KC + kq * 4);
        v2f h01 = {h4.x, h4.y}, h23 = {h4.z, h4.w};
        acc[t] = __builtin_elementwise_fma(h01, w01, acc[t]);
        acc[t] = __builtin_elementwise_fma(h23, w23, acc[t]);
      }
    }
    __syncthreads();
    pw += 8192;          // next 32KB weight chunk
    hoff += KC;          // next 128 k of hidden rows
  }

  // ---- epilogue: lane = expert; cross-lane softmax/top2 per token ----
  float o0 = 0.f, o1 = 0.f, oi0 = 0.f, oi1 = 0.f;
  float spacc = 0.f, cntacc = 0.f;
  #pragma unroll
  for (int t = 0; t < TW; ++t) {
    float lg = acc[t].x + acc[t].y;
    float m1 = lg;
    #pragma unroll
    for (int d = 1; d < 64; d <<= 1) m1 = fmaxf(m1, __shfl_xor(m1, d));
    int c0 = (lg == m1) ? lane : 64;
    #pragma unroll
    for (int d = 1; d < 64; d <<= 1) c0 = min(c0, __shfl_xor(c0, d));
    float lx = (lane == c0) ? -INFINITY : lg;
    float m2 = lx;
    #pragma unroll
    for (int d = 1; d < 64; d <<= 1) m2 = fmaxf(m2, __shfl_xor(m2, d));
    int c1 = (lx == m2) ? lane : 64;
    #pragma unroll
    for (int d = 1; d < 64; d <<= 1) c1 = min(c1, __shfl_xor(c1, d));
    float p = __expf(lg - m1);
    float Z = p;
    #pragma unroll
    for (int d = 1; d < 64; d <<= 1) Z += __shfl_xor(Z, d);
    spacc = fmaf(p, 1.f / Z, spacc);
    cntacc += ((lane == c0) ? 1.f : 0.f) + ((lane == c1) ? 1.f : 0.f);
    float g = __expf(m2 - m1);         // p(top2)/p(top1)
    float r0 = 1.f / (1.f + g);
    if (lane == t) { o0 = r0; o1 = g * r0; oi0 = (float)c0; oi1 = (float)c1; }
  }
  if (lane < TW) {
    int t = tok0 + wave * TW + lane;
    out[(size_t)t * 2]     = o0;
    out[(size_t)t * 2 + 1] = o1;
    out[(size_t)TOKENS * 2 + t * 2]     = oi0;
    out[(size_t)TOKENS * 2 + t * 2 + 1] = oi1;
  }

  // ---- block-level aux reduction (LDS reuse is safe: synced above loop exit) ----
  float* red = lds;
  red[wave * 128 + lane]      = spacc;
  red[wave * 128 + 64 + lane] = cntacc;
  __syncthreads();
  if (tid < 128) {
    float s = red[tid] + red[128 + tid] + red[256 + tid] + red[384 + tid];
    bp[(size_t)blockIdx.x * 128 + tid] = s;
  }
}

__global__ __launch_bounds__(128) void k_loss1(const float* __restrict__ bp,
                                               float* __restrict__ g2) {
  float s = 0.f;
  #pragma unroll 4
  for (int j = 0; j < 8; ++j)
    s += bp[(size_t)(blockIdx.x * 8 + j) * 128 + threadIdx.x];
  g2[(size_t)blockIdx.x * 128 + threadIdx.x] = s;
}

__global__ __launch_bounds__(128) void k_loss2(const float* __restrict__ g2,
                                               float* __restrict__ out) {
  const int tid = threadIdx.x;
  float s = 0.f;
  #pragma unroll 8
  for (int j = 0; j < 64; ++j) s += g2[(size_t)j * 128 + tid];
  __shared__ float red[128];
  red[tid] = s;
  __syncthreads();
  if (tid < 64) {
    float v = red[tid] * red[64 + tid];   // sumprob_e * count_e
    #pragma unroll
    for (int d = 1; d < 64; d <<= 1) v += __shfl_xor(v, d);
    if (tid == 0)
      out[(size_t)TOKENS * 4] = 0.01f * 64.f * v / (16384.f * 16384.f);
  }
}

extern "C" void kernel_launch(void* const* d_in, const int* in_sizes, int n_in,
                              void* d_out, int out_size, void* d_ws, size_t ws_size,
                              hipStream_t stream) {
  (void)in_sizes; (void)n_in; (void)out_size; (void)ws_size;
  const float* hid = (const float*)d_in[0];
  const float* gw  = (const float*)d_in[1];
  float* out = (float*)d_out;
  float* ws  = (float*)d_ws;
  float* wt4 = ws + WS_WT4;
  float* bp  = ws + WS_BP;
  float* g2  = ws + WS_G2;

  k_pack <<<128, 256, 0, stream>>>(gw, wt4);
  k_main <<<512, 256, 0, stream>>>(hid, wt4, out, bp);
  k_loss1<<<64, 128, 0, stream>>>(bp, g2);
  k_loss2<<<1, 128, 0, stream>>>(g2, out);
}

// Round 3
// 73.184 us; speedup vs baseline: 4.1446x; 2.3636x over previous
//
#include <hip/hip_runtime.h>
#include <math.h>

#define TOKENS 16384
#define HID    2048
#define KC     64
#define CHUNKS 32
#define TPB    64

typedef float f4 __attribute__((ext_vector_type(4)));
typedef short s8v __attribute__((ext_vector_type(8)));
typedef unsigned short u8v __attribute__((ext_vector_type(8)));

// ws layout: bytes [0,786432) = w1,w2,w3 bf16 planes [64][2048] (262144 B each)
// floats from 196608: bp [256][128]; g2 [32][128]
#define WSF_BP 196608
#define WSF_G2 229376

__device__ __forceinline__ void split3(float x, unsigned short& a, unsigned short& b,
                                       unsigned short& c) {
  unsigned u1 = __float_as_uint(x) & 0xFFFF0000u;
  float r = x - __uint_as_float(u1);
  unsigned u2 = __float_as_uint(r) & 0xFFFF0000u;
  float r2 = r - __uint_as_float(u2);
  a = (unsigned short)(u1 >> 16);
  b = (unsigned short)(u2 >> 16);
  c = (unsigned short)(__float_as_uint(r2) >> 16);
}

__device__ __forceinline__ void gl16(const void* g, const void* l) {
  __builtin_amdgcn_global_load_lds(
      (const __attribute__((address_space(1))) void*)g,
      (__attribute__((address_space(3))) void*)l, 16, 0, 0);
}

__global__ __launch_bounds__(256) void k_pack(const float* __restrict__ gw,
                                              unsigned short* __restrict__ w1,
                                              unsigned short* __restrict__ w2,
                                              unsigned short* __restrict__ w3) {
  int gid = blockIdx.x * 256 + threadIdx.x;  // 8192 threads, 16 floats each
  int e = gid >> 7, seg = gid & 127;
  const f4* src = (const f4*)(gw + (size_t)e * HID + seg * 16);
  unsigned short A1[16], A2[16], A3[16];
  #pragma unroll
  for (int i = 0; i < 4; ++i) {
    f4 v = src[i];
    #pragma unroll
    for (int k = 0; k < 4; ++k) split3(v[k], A1[i*4+k], A2[i*4+k], A3[i*4+k]);
  }
  size_t dst = (size_t)e * HID + seg * 16;
  #pragma unroll
  for (int j = 0; j < 2; ++j) {
    u8v x1, x2, x3;
    #pragma unroll
    for (int k = 0; k < 8; ++k) { x1[k]=A1[j*8+k]; x2[k]=A2[j*8+k]; x3[k]=A3[j*8+k]; }
    *(u8v*)(w1 + dst + j*8) = x1;
    *(u8v*)(w2 + dst + j*8) = x2;
    *(u8v*)(w3 + dst + j*8) = x3;
  }
}

#define BARK(N) { asm volatile("s_waitcnt vmcnt(" #N ") lgkmcnt(0)" ::: "memory"); \
  __builtin_amdgcn_sched_barrier(0); __builtin_amdgcn_s_barrier(); \
  __builtin_amdgcn_sched_barrier(0); }

#define ISSUEH(c, B) { const f4* gp_ = (const f4*)(hrow + (size_t)(c) * KC); \
  B##0 = gp_[0]; B##1 = gp_[1]; B##2 = gp_[2]; B##3 = gp_[3]; }

__global__ __launch_bounds__(256) void k_main(const float* __restrict__ hid,
    const unsigned short* __restrict__ w1, const unsigned short* __restrict__ w2,
    const unsigned short* __restrict__ w3,
    float* __restrict__ out, float* __restrict__ bp) {
  // LDS: buf b at b*49152: A planes p*8192 (3x8KB), W planes 24576+p*8192 (3x8KB)
  __shared__ __align__(16) char lds[98304];
  const int tid = threadIdx.x, wave = tid >> 6, lane = tid & 63;
  const int wi = wave >> 1, wj = wave & 1;
  const int q = lane >> 4, l15 = lane & 15;
  const int tok0 = blockIdx.x * TPB;

  int aoff[2], boff[2];
  #pragma unroll
  for (int mi = 0; mi < 2; ++mi) {
    int tl = (2*wi + mi) * 16 + l15;
    aoff[mi] = tl * 128 + ((q ^ (l15 & 7)) << 4);
  }
  #pragma unroll
  for (int nj = 0; nj < 2; ++nj) {
    int el = (2*wj + nj) * 16 + l15;
    boff[nj] = 24576 + el * 128 + ((q ^ (l15 & 7)) << 4);
  }

  // hidden staging: thread -> (token tid>>2, 16-float slice tid&3)
  const int tl_st = tid >> 2, s2 = tid & 3;
  const float* hrow = hid + (size_t)(tok0 + tl_st) * HID + s2 * 16;
  int awr[2];
  #pragma unroll
  for (int j = 0; j < 2; ++j)
    awr[j] = tl_st * 128 + (((2*s2 + j) ^ (tl_st & 7)) << 4);

  f4 z = {0.f, 0.f, 0.f, 0.f};
  f4 acc[2][2] = {{z, z}, {z, z}};

  auto issueW = [&](int c, int nb) {
    #pragma unroll
    for (int p = 0; p < 3; ++p) {
      const char* wp = (p == 0) ? (const char*)w1 : (p == 1) ? (const char*)w2
                                                             : (const char*)w3;
      #pragma unroll
      for (int i = 0; i < 2; ++i) {
        int u = i * 256 + tid;
        int e = u >> 3, seg = u & 7;
        gl16(wp + (size_t)e * 4096 + (size_t)c * 128 + ((seg ^ (e & 7)) << 4),
             lds + nb + 24576 + p * 8192 + i * 4096 + wave * 1024);
      }
    }
  };

  auto convH = [&](f4 v0, f4 v1, f4 v2, f4 v3, int nb) {
    unsigned short A1[16], A2[16], A3[16];
    f4 vv[4] = {v0, v1, v2, v3};
    #pragma unroll
    for (int i = 0; i < 4; ++i)
      #pragma unroll
      for (int k = 0; k < 4; ++k) split3(vv[i][k], A1[i*4+k], A2[i*4+k], A3[i*4+k]);
    #pragma unroll
    for (int j = 0; j < 2; ++j) {
      u8v x1, x2, x3;
      #pragma unroll
      for (int k = 0; k < 8; ++k) { x1[k]=A1[j*8+k]; x2[k]=A2[j*8+k]; x3[k]=A3[j*8+k]; }
      *(u8v*)(lds + nb + 0*8192 + awr[j]) = x1;
      *(u8v*)(lds + nb + 1*8192 + awr[j]) = x2;
      *(u8v*)(lds + nb + 2*8192 + awr[j]) = x3;
    }
  };

  auto compute = [&](int cb) {
    #pragma unroll
    for (int s = 0; s < 2; ++s) {
      s8v af[2][3], bf[2][3];
      #pragma unroll
      for (int mi = 0; mi < 2; ++mi)
        #pragma unroll
        for (int p = 0; p < 3; ++p)
          af[mi][p] = *(const s8v*)(lds + cb + p*8192 + (aoff[mi] ^ (s << 6)));
      #pragma unroll
      for (int nj = 0; nj < 2; ++nj)
        #pragma unroll
        for (int p = 0; p < 3; ++p)
          bf[nj][p] = *(const s8v*)(lds + cb + p*8192 + (boff[nj] ^ (s << 6)));
      #pragma unroll
      for (int mi = 0; mi < 2; ++mi)
        #pragma unroll
        for (int nj = 0; nj < 2; ++nj) {
          f4 A = acc[mi][nj];
          A = __builtin_amdgcn_mfma_f32_16x16x32_bf16(af[mi][0], bf[nj][0], A, 0, 0, 0);
          A = __builtin_amdgcn_mfma_f32_16x16x32_bf16(af[mi][0], bf[nj][1], A, 0, 0, 0);
          A = __builtin_amdgcn_mfma_f32_16x16x32_bf16(af[mi][1], bf[nj][0], A, 0, 0, 0);
          A = __builtin_amdgcn_mfma_f32_16x16x32_bf16(af[mi][0], bf[nj][2], A, 0, 0, 0);
          A = __builtin_amdgcn_mfma_f32_16x16x32_bf16(af[mi][1], bf[nj][1], A, 0, 0, 0);
          A = __builtin_amdgcn_mfma_f32_16x16x32_bf16(af[mi][2], bf[nj][0], A, 0, 0, 0);
          acc[mi][nj] = A;
        }
    }
  };

  f4 ha0, ha1, ha2, ha3, hb0, hb1, hb2, hb3;

  // prologue
  ISSUEH(0, ha);
  issueW(0, 0);
  ISSUEH(1, hb);
  convH(ha0, ha1, ha2, ha3, 0);
  __syncthreads();

  int bb = 0;
  #define STEP(c, BI, BC)                                          \
  {                                                                \
    const int nb = bb ^ 49152;                                     \
    if ((c) + 1 < CHUNKS) issueW((c) + 1, nb);                     \
    if ((c) + 2 < CHUNKS) ISSUEH((c) + 2, BI);                     \
    compute(bb);                                                   \
    if ((c) + 1 < CHUNKS) convH(BC##0, BC##1, BC##2, BC##3, nb);   \
    if ((c) + 2 < CHUNKS) { BARK(4); } else { BARK(0); }           \
    bb = nb;                                                       \
  }
  for (int cc = 0; cc < CHUNKS; cc += 2) {
    STEP(cc,     ha, hb);
    STEP(cc + 1, hb, ha);
  }

  // ---- epilogue: park logits in LDS as [64][68] f32, then R2-style per-token pass
  float* lf = (float*)lds;
  #pragma unroll
  for (int mi = 0; mi < 2; ++mi)
    #pragma unroll
    for (int nj = 0; nj < 2; ++nj) {
      f4 A = acc[mi][nj];
      int tl = (2*wi + mi) * 16 + q * 4;
      int e  = (2*wj + nj) * 16 + l15;
      #pragma unroll
      for (int r = 0; r < 4; ++r) lf[(tl + r) * 68 + e] = A[r];
    }
  __syncthreads();

  float o0 = 0.f, o1 = 0.f, oi0 = 0.f, oi1 = 0.f, spacc = 0.f, cntacc = 0.f;
  for (int t16 = 0; t16 < 16; ++t16) {
    float lg = lf[(wave * 16 + t16) * 68 + lane];
    float m1 = lg;
    #pragma unroll
    for (int d = 1; d < 64; d <<= 1) m1 = fmaxf(m1, __shfl_xor(m1, d));
    int c0 = (lg == m1) ? lane : 64;
    #pragma unroll
    for (int d = 1; d < 64; d <<= 1) c0 = min(c0, __shfl_xor(c0, d));
    float lx = (lane == c0) ? -INFINITY : lg;
    float m2 = lx;
    #pragma unroll
    for (int d = 1; d < 64; d <<= 1) m2 = fmaxf(m2, __shfl_xor(m2, d));
    int c1 = (lx == m2) ? lane : 64;
    #pragma unroll
    for (int d = 1; d < 64; d <<= 1) c1 = min(c1, __shfl_xor(c1, d));
    float p = __expf(lg - m1);
    float Z = p;
    #pragma unroll
    for (int d = 1; d < 64; d <<= 1) Z += __shfl_xor(Z, d);
    spacc = fmaf(p, 1.f / Z, spacc);
    cntacc += ((lane == c0) ? 1.f : 0.f) + ((lane == c1) ? 1.f : 0.f);
    float g = __expf(m2 - m1);
    float r0 = 1.f / (1.f + g);
    if (lane == t16) { o0 = r0; o1 = g * r0; oi0 = (float)c0; oi1 = (float)c1; }
  }
  if (lane < 16) {
    int t = tok0 + wave * 16 + lane;
    out[(size_t)t * 2]     = o0;
    out[(size_t)t * 2 + 1] = o1;
    out[(size_t)TOKENS * 2 + t * 2]     = oi0;
    out[(size_t)TOKENS * 2 + t * 2 + 1] = oi1;
  }
  __syncthreads();
  float* red = lf + 4608;
  red[wave * 128 + lane]      = spacc;
  red[wave * 128 + 64 + lane] = cntacc;
  __syncthreads();
  if (tid < 128) {
    float s = red[tid] + red[128 + tid] + red[256 + tid] + red[384 + tid];
    bp[(size_t)blockIdx.x * 128 + tid] = s;
  }
}

__global__ __launch_bounds__(128) void k_loss1(const float* __restrict__ bp,
                                               float* __restrict__ g2) {
  float s = 0.f;
  #pragma unroll 4
  for (int j = 0; j < 8; ++j)
    s += bp[(size_t)(blockIdx.x * 8 + j) * 128 + threadIdx.x];
  g2[(size_t)blockIdx.x * 128 + threadIdx.x] = s;
}

__global__ __launch_bounds__(128) void k_loss2(const float* __restrict__ g2,
                                               float* __restrict__ out) {
  const int tid = threadIdx.x;
  float s = 0.f;
  #pragma unroll 8
  for (int j = 0; j < 32; ++j) s += g2[(size_t)j * 128 + tid];
  __shared__ float red[128];
  red[tid] = s;
  __syncthreads();
  if (tid < 64) {
    float v = red[tid] * red[64 + tid];
    #pragma unroll
    for (int d = 1; d < 64; d <<= 1) v += __shfl_xor(v, d);
    if (tid == 0)
      out[(size_t)TOKENS * 4] = 0.01f * 64.f * v / (16384.f * 16384.f);
  }
}

extern "C" void kernel_launch(void* const* d_in, const int* in_sizes, int n_in,
                              void* d_out, int out_size, void* d_ws, size_t ws_size,
                              hipStream_t stream) {
  (void)in_sizes; (void)n_in; (void)out_size; (void)ws_size;
  const float* hid = (const float*)d_in[0];
  const float* gw  = (const float*)d_in[1];
  float* out = (float*)d_out;
  unsigned short* w1 = (unsigned short*)d_ws;
  unsigned short* w2 = w1 + 131072;
  unsigned short* w3 = w2 + 131072;
  float* bp = (float*)d_ws + WSF_BP;
  float* g2 = (float*)d_ws + WSF_G2;

  k_pack <<<32, 256, 0, stream>>>(gw, w1, w2, w3);
  k_main <<<256, 256, 0, stream>>>(hid, w1, w2, w3, out, bp);
  k_loss1<<<32, 128, 0, stream>>>(bp, g2);
  k_loss2<<<1, 128, 0, stream>>>(g2, out);
}